// Round 4
// baseline (299.422 us; speedup 1.0000x reference)
//
#include <hip/hip_runtime.h>
#include <hip/hip_bf16.h>
#include <math.h>

#define T_   2048
#define B_   2
#define E_   1024
#define H_   16
#define D_   64
#define NH_  32
#define M_   4096

typedef __attribute__((ext_vector_type(8))) short s8b;   // 8 bf16 (4 VGPRs)
typedef __attribute__((ext_vector_type(4))) float f4;    // 4 f32 acc

#define MFMA_B16(a,b,c) __builtin_amdgcn_mfma_f32_16x16x32_bf16(a,b,c,0,0,0)
#define LOG2E 1.44269504088896f

__device__ __forceinline__ unsigned short f2bu(float f) {
    union { __hip_bfloat16 h; unsigned short u; } cv;
    cv.h = __float2bfloat16(f);
    return cv.u;
}
// fast bf16: round-half-up truncation (positive finite values) — 2 VALU ops
__device__ __forceinline__ unsigned short f2bu_fast(float f) {
    return (unsigned short)((__float_as_uint(f) + 0x8000u) >> 16);
}
__device__ __forceinline__ float bu2f(unsigned short u) {
    union { __hip_bfloat16 h; unsigned short u; } cv; cv.u = u;
    return __bfloat162float(cv.h);
}
__device__ __forceinline__ unsigned int pk2(float a, float b) {
    return (unsigned int)f2bu(a) | ((unsigned int)f2bu(b) << 16);
}
// pack two f32 -> packed bf16 pair with round-half-up (cheap)
__device__ __forceinline__ unsigned int pk2_fast(float a, float b) {
    return ((__float_as_uint(a) + 0x8000u) >> 16) |
           ((__float_as_uint(b) + 0x8000u) & 0xFFFF0000u);
}
// raw v_exp_f32 — exp2f() without fast-math expands to a denorm-guard
// sequence (~12 extra VALU ops); attention scores never reach denormals.
__device__ __forceinline__ float fexp2(float x) {
    return __builtin_amdgcn_exp2f(x);
}
__device__ __forceinline__ float ld1d(const void* p, size_t idx, bool f32) {
    return f32 ? ((const float*)p)[idx] : bu2f(((const unsigned short*)p)[idx]);
}
// sum across the 4 quads (lane bits 4-5)
__device__ __forceinline__ float qsumq(float v) {
    v += __shfl_xor(v, 16); v += __shfl_xor(v, 32);
    return v;
}
// async global->LDS, 16 B per lane (GEMMs only)
__device__ __forceinline__ void glds16(const unsigned short* g, unsigned short* l) {
    __builtin_amdgcn_global_load_lds(
        (const __attribute__((address_space(1))) unsigned int*)g,
        (__attribute__((address_space(3))) unsigned int*)l, 16, 0, 0);
}
// dtype detect, wave-local (identical result in every wave): sample 64 u16
// words of x; bf16 data -> ~all exponent fields sane; f32-as-u16 -> ~half.
__device__ __forceinline__ bool detect_f32(const unsigned short* q16) {
    int e = (q16[threadIdx.x & 63] >> 7) & 0xFF;
    bool sane = (e == 0) || (e >= 97 && e <= 157);
    unsigned long long m = __ballot(sane);
    return __popcll(m) < 56;   // true = f32 inputs
}

// ---------------------------------------------------------------------------
// One-pass f32->bf16 conversion of x, Wq..Wo, bq..bo into ws. Also publishes
// the dtype flag (block (0,0) of the x region) for the attn/out kernels.
// ---------------------------------------------------------------------------
__global__ __launch_bounds__(256) void cvt_bf16(
    const void* __restrict__ x,
    const void* __restrict__ Wq, const void* __restrict__ Wk,
    const void* __restrict__ Wv, const void* __restrict__ Wo,
    const void* __restrict__ bq, const void* __restrict__ bk,
    const void* __restrict__ bv, const void* __restrict__ bo,
    unsigned short* __restrict__ xw, unsigned short* __restrict__ Ww,
    unsigned short* __restrict__ bw, int* __restrict__ flag)
{
    const bool f32m = detect_f32((const unsigned short*)x);
    if (blockIdx.x == 0 && blockIdx.y == 0 && threadIdx.x == 0)
        *flag = f32m ? 1 : 0;
    const int y = blockIdx.y;
    const void* src; unsigned short* dst; int n;
    if (y == 0)      { src = x; dst = xw; n = M_ * E_; }
    else if (y <= 4) {
        src = (y == 1) ? Wq : (y == 2) ? Wk : (y == 3) ? Wv : Wo;
        dst = Ww + (size_t)(y - 1) * E_ * E_; n = E_ * E_;
    } else {
        src = (y == 5) ? bq : (y == 6) ? bk : (y == 7) ? bv : bo;
        dst = bw + (size_t)(y - 5) * E_; n = E_;
    }
    int i = (blockIdx.x * 256 + threadIdx.x) * 8;
    if (i >= n) return;
    if (f32m) {
        const float* s = (const float*)src + i;
        float4 f0 = *(const float4*)s, f1 = *(const float4*)(s + 4);
        union { unsigned int d[4]; s8b v; } u;
        u.d[0] = pk2(f0.x, f0.y); u.d[1] = pk2(f0.z, f0.w);
        u.d[2] = pk2(f1.x, f1.y); u.d[3] = pk2(f1.z, f1.w);
        *(s8b*)(dst + i) = u.v;
    } else {
        *(s8b*)(dst + i) = *(const s8b*)((const unsigned short*)src + i);
    }
}

// ---------------------------------------------------------------------------
// QKV projection, bf16 MFMA GEMM, XCD swizzle, glds staging (xor-swizzled),
// double-buffered single-barrier. p==2 (V) is written TRANSPOSED [N][D][T].
// ---------------------------------------------------------------------------
__global__ __launch_bounds__(256, 3) void qkv_gemm(
    const unsigned short* __restrict__ xw, const unsigned short* __restrict__ Ww,
    const unsigned short* __restrict__ bw,
    unsigned short* __restrict__ qo, unsigned short* __restrict__ ko,
    unsigned short* __restrict__ vo)
{
    const int bid = blockIdx.x;            // 768 blocks
    const int r_ = bid & 7, s_ = bid >> 3;
    const int g = r_ + 8 * (s_ >> 3);      // group in [0,96): (m,p)
    const int e0 = (s_ & 7) * 128;
    const int m0 = (g & 31) * 128;
    const int p  = g >> 5;
    const unsigned short* W    = Ww + (size_t)p * E_ * E_;
    const unsigned short* bias = bw + (size_t)p * E_;
    const float scale = (p == 0) ? 0.125f * LOG2E : 1.0f;

    const int tid = threadIdx.x, w = tid >> 6, lane = tid & 63;
    const int quad = lane >> 4, lc = lane & 15;
    const int wx = w & 1, wy = w >> 1;

    __shared__ unsigned short a_s[2][128 * 32];
    __shared__ unsigned short b_s[2][128 * 32];

    f4 acc[4][4];
    #pragma unroll
    for (int i = 0; i < 4; i++)
        #pragma unroll
        for (int j = 0; j < 4; j++) acc[i][j] = (f4){0.f, 0.f, 0.f, 0.f};

    const int gr = lane >> 2;
    const int gc = (lane & 3) ^ ((lane >> 2) & 3);
    const size_t aoff = (size_t)(m0 + w*32 + gr) * E_ + gc*8;
    const size_t boff = (size_t)(e0 + w*32 + gr) * E_ + gc*8;

    #pragma unroll
    for (int j = 0; j < 2; j++) {
        glds16(xw + aoff + (size_t)j*16*E_, &a_s[0][(w*128 + j*64) * 8]);
        glds16(W  + boff + (size_t)j*16*E_, &b_s[0][(w*128 + j*64) * 8]);
    }
    __syncthreads();

    const int fcA = quad ^ (lc & 3);
    for (int k0 = 0; k0 < E_; k0 += 32) {
        const int cur = (k0 >> 5) & 1;
        if (k0 + 32 < E_) {
            #pragma unroll
            for (int j = 0; j < 2; j++) {
                glds16(xw + aoff + (size_t)j*16*E_ + k0 + 32, &a_s[cur^1][(w*128 + j*64) * 8]);
                glds16(W  + boff + (size_t)j*16*E_ + k0 + 32, &b_s[cur^1][(w*128 + j*64) * 8]);
            }
        }
        s8b af[4], bfr[4];
        #pragma unroll
        for (int i = 0; i < 4; i++)
            af[i]  = *(const s8b*)&a_s[cur][((wy*64 + i*16 + lc)*4 + fcA) * 8];
        #pragma unroll
        for (int i = 0; i < 4; i++)
            bfr[i] = *(const s8b*)&b_s[cur][((wx*64 + i*16 + lc)*4 + fcA) * 8];
        #pragma unroll
        for (int ms = 0; ms < 4; ms++)
            #pragma unroll
            for (int ns = 0; ns < 4; ns++)
                acc[ms][ns] = MFMA_B16(af[ms], bfr[ns], acc[ms][ns]);
        __syncthreads();
    }

    float bias_v[4];
    #pragma unroll
    for (int ns = 0; ns < 4; ns++) bias_v[ns] = bu2f(bias[e0 + wx*64 + ns*16 + lc]);

    if (p < 2) {
        #pragma unroll
        for (int ms = 0; ms < 4; ms++)
            #pragma unroll
            for (int ns = 0; ns < 4; ns++)
                #pragma unroll
                for (int r2 = 0; r2 < 4; r2++) {
                    float val = (acc[ms][ns][r2] + bias_v[ns]) * scale;
                    float nb = __shfl_xor(val, 1);
                    if (!(lane & 1)) {
                        int m = m0 + wy*64 + ms*16 + quad*4 + r2;
                        int t = m >> 1, bb = m & 1;
                        int e = e0 + wx*64 + ns*16 + lc;
                        int h = e >> 6, d = e & 63;
                        unsigned short* dst = (p == 0) ? qo : ko;
                        *(unsigned int*)&dst[(((size_t)(bb*H_ + h) * T_ + t) << 6) + d] = pk2(val, nb);
                    }
                }
    } else {
        // V transposed: vo[nh][d][t]
        #pragma unroll
        for (int ms = 0; ms < 4; ms++) {
            int t0v = (m0 + wy*64 + ms*16 + quad*4) >> 1;
            #pragma unroll
            for (int ns = 0; ns < 4; ns++) {
                int e = e0 + wx*64 + ns*16 + lc;
                int h = e >> 6, d = e & 63;
                float v0 = acc[ms][ns][0] + bias_v[ns];
                float v1 = acc[ms][ns][1] + bias_v[ns];
                float v2 = acc[ms][ns][2] + bias_v[ns];
                float v3 = acc[ms][ns][3] + bias_v[ns];
                *(unsigned int*)&vo[((size_t)h        * 64 + d) * T_ + t0v] = pk2(v0, v2);
                *(unsigned int*)&vo[((size_t)(H_ + h) * 64 + d) * T_ + t0v] = pk2(v1, v3);
            }
        }
    }
}

// ---------------------------------------------------------------------------
// Flash attention with Shaw bias — R15: barrier-free main loop.
// 128-row Q-tiles (R13 geometry, known-good), but K/V fragments are loaded
// DIRECTLY from global (L1/L2-resident: 256 KB K + 256 KB V per head;
// FETCH_SIZE showed HBM at 3% — staging through LDS was pure overhead,
// and its per-tile __syncthreads() lockstepped all 4 waves). K is register
// double-buffered across tiles; V issues at tile-top and is consumed after
// the S+exp phase (~400 cy of cover for ~200-300 cy L2 latency). The only
// remaining LDS use is wave-private (p_s, diag16) or read-only (qrk_s),
// so the main loop has NO barriers: 8 waves/CU drift freely and fill each
// other's dependency stalls.
// ---------------------------------------------------------------------------
__global__ __launch_bounds__(256, 2) void attn_mfma(
    const unsigned short* __restrict__ q, const unsigned short* __restrict__ k,
    const unsigned short* __restrict__ v,
    const void* __restrict__ rk_t, const void* __restrict__ rv_t,
    unsigned short* __restrict__ aout, const int* __restrict__ flag)
{
    const bool f32m = (*flag != 0);
    const int bid = blockIdx.x;
    const int n = bid & 31, qt = bid >> 5;
    const int t0 = qt * 128;
    const int tid = threadIdx.x, w = tid >> 6, lane = tid & 63;
    const int quad = lane >> 4, lc = lane & 15;

    __shared__ unsigned short p_s[4][32 * 72];   // per-wave P[t][s] / P_extra; rk staging
    __shared__ unsigned short qrk_s[128 * 36];   // qrk[t_local][r] bf16; rv^T in epilogue
    __shared__ unsigned short diag16[128 * 33];  // e-values at |rel|<16, bf16
    __shared__ float st_L[128], st_R[128];

    const unsigned short* qn = q + ((size_t)n * T_ + t0) * D_;
    const unsigned short* kn = k + (size_t)n * T_ * D_;
    const unsigned short* vn = v + (size_t)n * D_ * T_;   // V^T [D][T]

    // Q fragments (B-operand for S^T)
    s8b qa[2][2];
    #pragma unroll
    for (int nt = 0; nt < 2; nt++)
        #pragma unroll
        for (int kf = 0; kf < 2; kf++)
            qa[nt][kf] = *(const s8b*)(qn + (size_t)(w*32 + nt*16 + lc) * D_ + kf*32 + quad*8);

    for (int i = tid; i < 128 * 33; i += 256) diag16[i] = 0;

    // stage rk (bf16, padded [48][72], rows>=33 zero) into p_s area
    unsigned int* rks = (unsigned int*)&p_s[0][0];
    for (int i = tid; i < 48 * 36; i += 256) {
        int r = i / 36, c2 = i % 36;
        unsigned int val = 0;
        if (r < 33 && c2 < 32)
            val = pk2(ld1d(rk_t, r*64 + 2*c2, f32m), ld1d(rk_t, r*64 + 2*c2 + 1, f32m));
        rks[i] = val;
    }
    __syncthreads();

    // qrk[t][r] = q[t] . rk[r] via MFMA (prologue-only)
    #pragma unroll
    for (int mt = 0; mt < 2; mt++)
        for (int nt = 0; nt < 3; nt++) {
            s8b b0 = *(const s8b*)((const unsigned short*)rks + (nt*16 + lc)*72 + quad*8);
            s8b b1 = *(const s8b*)((const unsigned short*)rks + (nt*16 + lc)*72 + 32 + quad*8);
            f4 a = (f4){0.f, 0.f, 0.f, 0.f};
            a = MFMA_B16(qa[mt][0], b0, a);
            a = MFMA_B16(qa[mt][1], b1, a);
            #pragma unroll
            for (int r = 0; r < 4; r++) {
                float nb = __shfl_xor(a[r], 1);
                int col = nt*16 + lc;
                if (!(lane & 1) && col < 34)
                    ((unsigned int*)qrk_s)[(w*32 + mt*16 + quad*4 + r)*18 + (col >> 1)] = pk2(a[r], nb);
            }
        }
    __syncthreads();   // rk staging (aliased with p_s) free after this

    // per-lane Shaw edge biases (t = w*32 + nt*16 + lc)
    float qLn[2], qRn[2];
    float L_p[2] = {0.f, 0.f}, R_p[2] = {0.f, 0.f};
    f4 O[4][2], lsN[2], lsL[2], lsR[2];
    #pragma unroll
    for (int nt = 0; nt < 2; nt++) {
        int row = w*32 + nt*16 + lc;
        qLn[nt] = bu2f(qrk_s[row*36 + 0]);
        qRn[nt] = bu2f(qrk_s[row*36 + 32]);
        lsN[nt] = (f4){0.f, 0.f, 0.f, 0.f};
        lsL[nt] = (f4){0.f, 0.f, 0.f, 0.f};
        lsR[nt] = (f4){0.f, 0.f, 0.f, 0.f};
        #pragma unroll
        for (int dt = 0; dt < 4; dt++) O[dt][nt] = (f4){0.f, 0.f, 0.f, 0.f};
    }
    const short ob = (short)0x3F80;   // bf16 1.0
    const s8b ones = { ob, ob, ob, ob, ob, ob, ob, ob };

    const int lc7 = lc & 7;

    // one K/V tile: S^T -> exp/bias -> P (wave-private LDS) -> rowsum+PV.
    // cK = this tile's K frags (already loaded); nK = next tile's (issued here).
    auto tile_body = [&](s8b (&cK)[4][2], s8b (&nK)[4][2], int kt) {
        const int s0 = kt * 64;
        const int s0n = (kt < 31) ? s0 + 64 : s0;   // tail: harmless reload
        // issue next-tile K fragment loads (direct global; L1/L2-served)
        #pragma unroll
        for (int st = 0; st < 4; st++)
            #pragma unroll
            for (int kf = 0; kf < 2; kf++)
                nK[st][kf] = *(const s8b*)(kn + (size_t)(s0n + st*16 + lc) * D_ + kf*32 + quad*8);
        // issue current-tile V fragments; consumed after S+exp phase
        s8b cv[4][2];
        #pragma unroll
        for (int dt = 0; dt < 4; dt++)
            #pragma unroll
            for (int kf = 0; kf < 2; kf++)
                cv[dt][kf] = *(const s8b*)(vn + (size_t)(dt*16 + lc) * T_ + s0 + kf*32 + quad*8);

        const bool farL  = (s0 + 63 < t0 - 16);
        const bool farR  = (s0 > t0 + 143);
        const bool nearT = !farL && !farR;

        // S^T = K·Q^T (+ bias), exp2, pack b64 into P[t][s]
        #pragma unroll
        for (int st = 0; st < 4; st++)
            #pragma unroll
            for (int nt = 0; nt < 2; nt++) {
                f4 a;
                if (nearT) a = (f4){0.f, 0.f, 0.f, 0.f};
                else {
                    float qb = farL ? qLn[nt] : qRn[nt];
                    a = (f4){qb, qb, qb, qb};
                }
                a = MFMA_B16(cK[st][0], qa[nt][0], a);
                a = MFMA_B16(cK[st][1], qa[nt][1], a);
                unsigned int lo, hi;
                if (nearT) {
                    const int t_l = w*32 + nt*16 + lc;
                    const int sb  = s0 + st*16 + quad*4 - (t0 + t_l);
                    unsigned short eb[4];
                    #pragma unroll
                    for (int r = 0; r < 4; r++) {
                        int rel = sb + r;
                        int rc = rel < -16 ? -16 : (rel > 16 ? 16 : rel);
                        float e = fexp2(a[r] + bu2f(qrk_s[t_l*36 + rc + 16]));
                        eb[r] = f2bu_fast(e);
                        if (rel <= -16)      L_p[nt] += e;
                        else if (rel >= 16)  R_p[nt] += e;
                        else                 diag16[t_l*33 + rel + 15] = eb[r];
                    }
                    lo = (unsigned int)eb[0] | ((unsigned int)eb[1] << 16);
                    hi = (unsigned int)eb[2] | ((unsigned int)eb[3] << 16);
                } else {
                    lo = pk2_fast(fexp2(a[0]), fexp2(a[1]));
                    hi = pk2_fast(fexp2(a[2]), fexp2(a[3]));
                }
                *(uint2*)&p_s[w][(nt*16 + lc)*72 + st*16 + quad*4] = make_uint2(lo, hi);
            }

        // P fragments (B-operand): P[t=lc][s=quad*8+j]
        s8b pb[2][2];
        #pragma unroll
        for (int nt = 0; nt < 2; nt++) {
            pb[nt][0] = *(const s8b*)&p_s[w][(nt*16 + lc)*72 + quad*8];
            pb[nt][1] = *(const s8b*)&p_s[w][(nt*16 + lc)*72 + 32 + quad*8];
        }
        // column sums of P^T (= row sums of P) via ones-MFMA
        if (nearT) {
            #pragma unroll
            for (int nt = 0; nt < 2; nt++) {
                lsN[nt] = MFMA_B16(ones, pb[nt][0], lsN[nt]);
                lsN[nt] = MFMA_B16(ones, pb[nt][1], lsN[nt]);
            }
        } else if (farL) {
            #pragma unroll
            for (int nt = 0; nt < 2; nt++) {
                lsL[nt] = MFMA_B16(ones, pb[nt][0], lsL[nt]);
                lsL[nt] = MFMA_B16(ones, pb[nt][1], lsL[nt]);
            }
        } else {
            #pragma unroll
            for (int nt = 0; nt < 2; nt++) {
                lsR[nt] = MFMA_B16(ones, pb[nt][0], lsR[nt]);
                lsR[nt] = MFMA_B16(ones, pb[nt][1], lsR[nt]);
            }
        }
        // O^T += V^T · P^T
        #pragma unroll
        for (int dt = 0; dt < 4; dt++) {
            O[dt][0] = MFMA_B16(cv[dt][0], pb[0][0], O[dt][0]);
            O[dt][0] = MFMA_B16(cv[dt][1], pb[0][1], O[dt][0]);
            O[dt][1] = MFMA_B16(cv[dt][0], pb[1][0], O[dt][1]);
            O[dt][1] = MFMA_B16(cv[dt][1], pb[1][1], O[dt][1]);
        }
    };

    // K register double-buffer, compile-time swapped (no dynamic indexing)
    s8b kA[4][2], kB[4][2];
    #pragma unroll
    for (int st = 0; st < 4; st++)
        #pragma unroll
        for (int kf = 0; kf < 2; kf++)
            kA[st][kf] = *(const s8b*)(kn + (size_t)(st*16 + lc) * D_ + kf*32 + quad*8);

    for (int kt2 = 0; kt2 < 32; kt2 += 2) {
        tile_body(kA, kB, kt2);
        tile_body(kB, kA, kt2 + 1);
    }

    // ---- epilogue: totals, relpos-V via rv^T·P_extra^T, normalize, store ----
    float linv[2];
    #pragma unroll
    for (int nt = 0; nt < 2; nt++) {
        float l = lsN[nt][0] + lsL[nt][0] + lsR[nt][0];
        float L = lsL[nt][0] + qsumq(L_p[nt]);
        float R = lsR[nt][0] + qsumq(R_p[nt]);
        linv[nt] = 1.f / l;
        if (quad == 0) {
            int row = w*32 + nt*16 + lc;
            st_L[row] = L; st_R[row] = R;
        }
    }
    __syncthreads();   // all waves done reading qrk_s (main loop) before reuse
    // stage rv TRANSPOSED into qrk_s with the xor swizzle (r>=33 zero)
    {
        unsigned int* rvs = (unsigned int*)&qrk_s[0];
        for (int i = tid; i < 64 * 32; i += 256) {
            int d = i >> 5, dwL = i & 31;
            int r0 = dwL * 2, r1 = r0 + 1;
            float x0 = (r0 < 33) ? ld1d(rv_t, (size_t)r0 * 64 + d, f32m) : 0.f;
            float x1 = (r1 < 33) ? ld1d(rv_t, (size_t)r1 * 64 + d, f32m) : 0.f;
            int phys = d * 32 + ((dwL >> 2) ^ (d & 7)) * 4 + (dwL & 3);
            rvs[phys] = pk2(x0, x1);
        }
    }
    __syncthreads();
    // build P_extra[32][64] bf16 in own wave region (cols 33..63 = 0)
    for (int j = 0; j < 32; j++) {
        int c = lane;
        int row = w*32 + j;
        unsigned short pv;
        if (c == 0)        pv = f2bu(st_L[row]);
        else if (c == 32)  pv = f2bu(st_R[row]);
        else if (c < 32)   pv = diag16[row*33 + c - 1];
        else               pv = 0;
        p_s[w][j*72 + c] = pv;
    }
    // O^T += rv^T · P_extra^T
    s8b pe[2][2];
    #pragma unroll
    for (int nt = 0; nt < 2; nt++) {
        pe[nt][0] = *(const s8b*)&p_s[w][(nt*16 + lc)*72 + quad*8];
        pe[nt][1] = *(const s8b*)&p_s[w][(nt*16 + lc)*72 + 32 + quad*8];
    }
    #pragma unroll
    for (int dt = 0; dt < 4; dt++) {
        int row = dt*16 + lc;
        s8b a0 = *(const s8b*)&qrk_s[(row*8 + (quad       ^ lc7)) * 8];
        s8b a1 = *(const s8b*)&qrk_s[(row*8 + ((4 + quad) ^ lc7)) * 8];
        O[dt][0] = MFMA_B16(a0, pe[0][0], O[dt][0]);
        O[dt][0] = MFMA_B16(a1, pe[0][1], O[dt][0]);
        O[dt][1] = MFMA_B16(a0, pe[1][0], O[dt][1]);
        O[dt][1] = MFMA_B16(a1, pe[1][1], O[dt][1]);
    }
    // normalize + store bf16 [T][B][E] — packed 8B store, no shfl
    const int bb = n >> 4, h = n & 15;
    #pragma unroll
    for (int nt = 0; nt < 2; nt++) {
        int t_g = t0 + w*32 + nt*16 + lc;
        #pragma unroll
        for (int dt = 0; dt < 4; dt++) {
            float v0 = O[dt][nt][0] * linv[nt];
            float v1 = O[dt][nt][1] * linv[nt];
            float v2 = O[dt][nt][2] * linv[nt];
            float v3 = O[dt][nt][3] * linv[nt];
            int e = h*64 + dt*16 + quad*4;
            *(uint2*)&aout[((size_t)t_g * B_ + bb) * E_ + e] =
                make_uint2(pk2(v0, v1), pk2(v2, v3));
        }
    }
}

// ---------------------------------------------------------------------------
// Output projection, bf16 MFMA GEMM, XCD swizzle, glds staging, dbuf.
// ---------------------------------------------------------------------------
__global__ __launch_bounds__(256, 3) void out_gemm(
    const unsigned short* __restrict__ A,
    const unsigned short* __restrict__ Wob, const unsigned short* __restrict__ bob,
    void* __restrict__ out, const int* __restrict__ flag)
{
    const bool f32m = (*flag != 0);
    const int bid = blockIdx.x;            // 256 blocks
    const int r_ = bid & 7, s_ = bid >> 3;
    const int g = r_ + 8 * (s_ >> 3);
    const int m0 = g * 128;
    const int e0 = (s_ & 7) * 128;

    const int tid = threadIdx.x, w = tid >> 6, lane = tid & 63;
    const int quad = lane >> 4, lc = lane & 15;
    const int wx = w & 1, wy = w >> 1;

    __shared__ unsigned short a_s[2][128 * 32];
    __shared__ unsigned short b_s[2][128 * 32];

    f4 acc[4][4];
    #pragma unroll
    for (int i = 0; i < 4; i++)
        #pragma unroll
        for (int j = 0; j < 4; j++) acc[i][j] = (f4){0.f, 0.f, 0.f, 0.f};

    const int gr = lane >> 2;
    const int gc = (lane & 3) ^ ((lane >> 2) & 3);
    const size_t aoff = (size_t)(m0 + w*32 + gr) * E_ + gc*8;
    const size_t boff = (size_t)(e0 + w*32 + gr) * E_ + gc*8;

    #pragma unroll
    for (int j = 0; j < 2; j++) {
        glds16(A   + aoff + (size_t)j*16*E_, &a_s[0][(w*128 + j*64) * 8]);
        glds16(Wob + boff + (size_t)j*16*E_, &b_s[0][(w*128 + j*64) * 8]);
    }
    __syncthreads();

    const int fcA = quad ^ (lc & 3);
    for (int k0 = 0; k0 < E_; k0 += 32) {
        const int cur = (k0 >> 5) & 1;
        if (k0 + 32 < E_) {
            #pragma unroll
            for (int j = 0; j < 2; j++) {
                glds16(A   + aoff + (size_t)j*16*E_ + k0 + 32, &a_s[cur^1][(w*128 + j*64) * 8]);
                glds16(Wob + boff + (size_t)j*16*E_ + k0 + 32, &b_s[cur^1][(w*128 + j*64) * 8]);
            }
        }
        s8b af[4], bfr[4];
        #pragma unroll
        for (int i = 0; i < 4; i++)
            af[i]  = *(const s8b*)&a_s[cur][((wy*64 + i*16 + lc)*4 + fcA) * 8];
        #pragma unroll
        for (int i = 0; i < 4; i++)
            bfr[i] = *(const s8b*)&b_s[cur][((wx*64 + i*16 + lc)*4 + fcA) * 8];
        #pragma unroll
        for (int ms = 0; ms < 4; ms++)
            #pragma unroll
            for (int ns = 0; ns < 4; ns++)
                acc[ms][ns] = MFMA_B16(af[ms], bfr[ns], acc[ms][ns]);
        __syncthreads();
    }

    float bias_v[4];
    #pragma unroll
    for (int ns = 0; ns < 4; ns++) bias_v[ns] = bu2f(bob[e0 + wx*64 + ns*16 + lc]);

    #pragma unroll
    for (int ms = 0; ms < 4; ms++)
        #pragma unroll
        for (int ns = 0; ns < 4; ns++)
            #pragma unroll
            for (int r2 = 0; r2 < 4; r2++) {
                float val = acc[ms][ns][r2] + bias_v[ns];
                size_t m = m0 + wy*64 + ms*16 + quad*4 + r2;
                int e = e0 + wx*64 + ns*16 + lc;
                if (f32m) {
                    ((float*)out)[m * E_ + e] = val;
                } else {
                    float nb = __shfl_xor(val, 1);
                    if (!(lane & 1))
                        *(unsigned int*)&((unsigned short*)out)[m * E_ + e] = pk2(val, nb);
                }
            }
}

extern "C" void kernel_launch(void* const* d_in, const int* in_sizes, int n_in,
                              void* d_out, int out_size, void* d_ws, size_t ws_size,
                              hipStream_t stream) {
    const void* x  = d_in[0];
    const void* Wq = d_in[1];  const void* bq = d_in[2];
    const void* Wk = d_in[3];  const void* bk = d_in[4];
    const void* Wv = d_in[5];  const void* bv = d_in[6];
    const void* Wo = d_in[7];  const void* bo = d_in[8];
    const void* rk = d_in[9];  const void* rv = d_in[10];

    int* flag = (int*)d_ws;
    const size_t HTD = (size_t)NH_ * T_ * D_;        // 4,194,304 elems
    unsigned short* qw = (unsigned short*)((char*)d_ws + 256);
    unsigned short* kw = qw + HTD;
    unsigned short* vw = kw + HTD;                   // V^T [N][D][T] bf16
    unsigned short* aw = vw + HTD;                   // [4096][1024] bf16 pre-Wo
    unsigned short* xw = aw + (size_t)M_ * E_;       // x as bf16 (8 MB)
    unsigned short* Ww = xw + (size_t)M_ * E_;       // Wq,Wk,Wv,Wo bf16 (8 MB)
    unsigned short* bw = Ww + (size_t)4 * E_ * E_;   // bq,bk,bv,bo bf16 (8 KB)
    // ws use: ~48 MB

    cvt_bf16<<<dim3((M_*E_/8 + 255)/256, 9), 256, 0, stream>>>(
        x, Wq, Wk, Wv, Wo, bq, bk, bv, bo, xw, Ww, bw, flag);
    qkv_gemm<<<dim3(768), 256, 0, stream>>>(xw, Ww, bw, qw, kw, vw);
    attn_mfma<<<dim3(NH_ * (T_/128)), 256, 0, stream>>>(qw, kw, vw, rk, rv, aw, flag);
    out_gemm<<<dim3(256), 256, 0, stream>>>(aw, Ww + (size_t)3*E_*E_, bw + 3*E_,
                                            d_out, flag);
}

// Round 5
// 235.656 us; speedup vs baseline: 1.2706x; 1.2706x over previous
//
#include <hip/hip_runtime.h>
#include <hip/hip_bf16.h>
#include <math.h>

#define T_   2048
#define B_   2
#define E_   1024
#define H_   16
#define D_   64
#define NH_  32
#define M_   4096

typedef __attribute__((ext_vector_type(8))) short s8b;   // 8 bf16 (4 VGPRs)
typedef __attribute__((ext_vector_type(4))) float f4;    // 4 f32 acc

#define MFMA_B16(a,b,c) __builtin_amdgcn_mfma_f32_16x16x32_bf16(a,b,c,0,0,0)
#define LOG2E 1.44269504088896f

__device__ __forceinline__ unsigned short f2bu(float f) {
    union { __hip_bfloat16 h; unsigned short u; } cv;
    cv.h = __float2bfloat16(f);
    return cv.u;
}
// fast bf16: round-half-up truncation (positive finite values) — 2 VALU ops
__device__ __forceinline__ unsigned short f2bu_fast(float f) {
    return (unsigned short)((__float_as_uint(f) + 0x8000u) >> 16);
}
__device__ __forceinline__ float bu2f(unsigned short u) {
    union { __hip_bfloat16 h; unsigned short u; } cv; cv.u = u;
    return __bfloat162float(cv.h);
}
__device__ __forceinline__ unsigned int pk2(float a, float b) {
    return (unsigned int)f2bu(a) | ((unsigned int)f2bu(b) << 16);
}
// pack two f32 -> packed bf16 pair with round-half-up (cheap)
__device__ __forceinline__ unsigned int pk2_fast(float a, float b) {
    return ((__float_as_uint(a) + 0x8000u) >> 16) |
           ((__float_as_uint(b) + 0x8000u) & 0xFFFF0000u);
}
// raw v_exp_f32 — exp2f() without fast-math expands to a denorm-guard
// sequence (~12 extra VALU ops); attention scores never reach denormals.
__device__ __forceinline__ float fexp2(float x) {
    return __builtin_amdgcn_exp2f(x);
}
__device__ __forceinline__ float ld1d(const void* p, size_t idx, bool f32) {
    return f32 ? ((const float*)p)[idx] : bu2f(((const unsigned short*)p)[idx]);
}
// sum across the 4 quads (lane bits 4-5)
__device__ __forceinline__ float qsumq(float v) {
    v += __shfl_xor(v, 16); v += __shfl_xor(v, 32);
    return v;
}
// async global->LDS, 16 B per lane (GEMMs only — attn uses register prefetch
// because its per-tile barrier drains vmcnt(0) and exposes the DMA latency)
__device__ __forceinline__ void glds16(const unsigned short* g, unsigned short* l) {
    __builtin_amdgcn_global_load_lds(
        (const __attribute__((address_space(1))) unsigned int*)g,
        (__attribute__((address_space(3))) unsigned int*)l, 16, 0, 0);
}
// dtype detect, wave-local (identical result in every wave): sample 64 u16
// words of x; bf16 data -> ~all exponent fields sane; f32-as-u16 -> ~half.
__device__ __forceinline__ bool detect_f32(const unsigned short* q16) {
    int e = (q16[threadIdx.x & 63] >> 7) & 0xFF;
    bool sane = (e == 0) || (e >= 97 && e <= 157);
    unsigned long long m = __ballot(sane);
    return __popcll(m) < 56;   // true = f32 inputs
}

// ---------------------------------------------------------------------------
// One-pass f32->bf16 conversion of x, Wq..Wo, bq..bo into ws. Also publishes
// the dtype flag (block (0,0) of the x region) for the attn/out kernels.
// ---------------------------------------------------------------------------
__global__ __launch_bounds__(256) void cvt_bf16(
    const void* __restrict__ x,
    const void* __restrict__ Wq, const void* __restrict__ Wk,
    const void* __restrict__ Wv, const void* __restrict__ Wo,
    const void* __restrict__ bq, const void* __restrict__ bk,
    const void* __restrict__ bv, const void* __restrict__ bo,
    unsigned short* __restrict__ xw, unsigned short* __restrict__ Ww,
    unsigned short* __restrict__ bw, int* __restrict__ flag)
{
    const bool f32m = detect_f32((const unsigned short*)x);
    if (blockIdx.x == 0 && blockIdx.y == 0 && threadIdx.x == 0)
        *flag = f32m ? 1 : 0;
    const int y = blockIdx.y;
    const void* src; unsigned short* dst; int n;
    if (y == 0)      { src = x; dst = xw; n = M_ * E_; }
    else if (y <= 4) {
        src = (y == 1) ? Wq : (y == 2) ? Wk : (y == 3) ? Wv : Wo;
        dst = Ww + (size_t)(y - 1) * E_ * E_; n = E_ * E_;
    } else {
        src = (y == 5) ? bq : (y == 6) ? bk : (y == 7) ? bv : bo;
        dst = bw + (size_t)(y - 5) * E_; n = E_;
    }
    int i = (blockIdx.x * 256 + threadIdx.x) * 8;
    if (i >= n) return;
    if (f32m) {
        const float* s = (const float*)src + i;
        float4 f0 = *(const float4*)s, f1 = *(const float4*)(s + 4);
        union { unsigned int d[4]; s8b v; } u;
        u.d[0] = pk2(f0.x, f0.y); u.d[1] = pk2(f0.z, f0.w);
        u.d[2] = pk2(f1.x, f1.y); u.d[3] = pk2(f1.z, f1.w);
        *(s8b*)(dst + i) = u.v;
    } else {
        *(s8b*)(dst + i) = *(const s8b*)((const unsigned short*)src + i);
    }
}

// ---------------------------------------------------------------------------
// QKV projection, bf16 MFMA GEMM, XCD swizzle, glds staging (xor-swizzled),
// double-buffered single-barrier. p==2 (V) is written TRANSPOSED [N][D][T].
// ---------------------------------------------------------------------------
__global__ __launch_bounds__(256, 3) void qkv_gemm(
    const unsigned short* __restrict__ xw, const unsigned short* __restrict__ Ww,
    const unsigned short* __restrict__ bw,
    unsigned short* __restrict__ qo, unsigned short* __restrict__ ko,
    unsigned short* __restrict__ vo)
{
    const int bid = blockIdx.x;            // 768 blocks
    const int r_ = bid & 7, s_ = bid >> 3;
    const int g = r_ + 8 * (s_ >> 3);      // group in [0,96): (m,p)
    const int e0 = (s_ & 7) * 128;
    const int m0 = (g & 31) * 128;
    const int p  = g >> 5;
    const unsigned short* W    = Ww + (size_t)p * E_ * E_;
    const unsigned short* bias = bw + (size_t)p * E_;
    const float scale = (p == 0) ? 0.125f * LOG2E : 1.0f;

    const int tid = threadIdx.x, w = tid >> 6, lane = tid & 63;
    const int quad = lane >> 4, lc = lane & 15;
    const int wx = w & 1, wy = w >> 1;

    __shared__ unsigned short a_s[2][128 * 32];
    __shared__ unsigned short b_s[2][128 * 32];

    f4 acc[4][4];
    #pragma unroll
    for (int i = 0; i < 4; i++)
        #pragma unroll
        for (int j = 0; j < 4; j++) acc[i][j] = (f4){0.f, 0.f, 0.f, 0.f};

    const int gr = lane >> 2;
    const int gc = (lane & 3) ^ ((lane >> 2) & 3);
    const size_t aoff = (size_t)(m0 + w*32 + gr) * E_ + gc*8;
    const size_t boff = (size_t)(e0 + w*32 + gr) * E_ + gc*8;

    #pragma unroll
    for (int j = 0; j < 2; j++) {
        glds16(xw + aoff + (size_t)j*16*E_, &a_s[0][(w*128 + j*64) * 8]);
        glds16(W  + boff + (size_t)j*16*E_, &b_s[0][(w*128 + j*64) * 8]);
    }
    __syncthreads();

    const int fcA = quad ^ (lc & 3);
    for (int k0 = 0; k0 < E_; k0 += 32) {
        const int cur = (k0 >> 5) & 1;
        if (k0 + 32 < E_) {
            #pragma unroll
            for (int j = 0; j < 2; j++) {
                glds16(xw + aoff + (size_t)j*16*E_ + k0 + 32, &a_s[cur^1][(w*128 + j*64) * 8]);
                glds16(W  + boff + (size_t)j*16*E_ + k0 + 32, &b_s[cur^1][(w*128 + j*64) * 8]);
            }
        }
        s8b af[4], bfr[4];
        #pragma unroll
        for (int i = 0; i < 4; i++)
            af[i]  = *(const s8b*)&a_s[cur][((wy*64 + i*16 + lc)*4 + fcA) * 8];
        #pragma unroll
        for (int i = 0; i < 4; i++)
            bfr[i] = *(const s8b*)&b_s[cur][((wx*64 + i*16 + lc)*4 + fcA) * 8];
        #pragma unroll
        for (int ms = 0; ms < 4; ms++)
            #pragma unroll
            for (int ns = 0; ns < 4; ns++)
                acc[ms][ns] = MFMA_B16(af[ms], bfr[ns], acc[ms][ns]);
        __syncthreads();
    }

    float bias_v[4];
    #pragma unroll
    for (int ns = 0; ns < 4; ns++) bias_v[ns] = bu2f(bias[e0 + wx*64 + ns*16 + lc]);

    if (p < 2) {
        #pragma unroll
        for (int ms = 0; ms < 4; ms++)
            #pragma unroll
            for (int ns = 0; ns < 4; ns++)
                #pragma unroll
                for (int r2 = 0; r2 < 4; r2++) {
                    float val = (acc[ms][ns][r2] + bias_v[ns]) * scale;
                    float nb = __shfl_xor(val, 1);
                    if (!(lane & 1)) {
                        int m = m0 + wy*64 + ms*16 + quad*4 + r2;
                        int t = m >> 1, bb = m & 1;
                        int e = e0 + wx*64 + ns*16 + lc;
                        int h = e >> 6, d = e & 63;
                        unsigned short* dst = (p == 0) ? qo : ko;
                        *(unsigned int*)&dst[(((size_t)(bb*H_ + h) * T_ + t) << 6) + d] = pk2(val, nb);
                    }
                }
    } else {
        // V transposed: vo[nh][d][t]
        #pragma unroll
        for (int ms = 0; ms < 4; ms++) {
            int t0v = (m0 + wy*64 + ms*16 + quad*4) >> 1;
            #pragma unroll
            for (int ns = 0; ns < 4; ns++) {
                int e = e0 + wx*64 + ns*16 + lc;
                int h = e >> 6, d = e & 63;
                float v0 = acc[ms][ns][0] + bias_v[ns];
                float v1 = acc[ms][ns][1] + bias_v[ns];
                float v2 = acc[ms][ns][2] + bias_v[ns];
                float v3 = acc[ms][ns][3] + bias_v[ns];
                *(unsigned int*)&vo[((size_t)h        * 64 + d) * T_ + t0v] = pk2(v0, v2);
                *(unsigned int*)&vo[((size_t)(H_ + h) * 64 + d) * T_ + t0v] = pk2(v1, v3);
            }
        }
    }
}

// ---------------------------------------------------------------------------
// Flash attention with Shaw bias — R16: R13 structure (LDS-staged K/V,
// 128-row Q-tiles, 1 barrier/tile — proven best vs R14/R15) + cross-tile
// software pipeline: tile kt-1's rowsum+PV (20 register-only MFMAs) is
// deferred into iteration kt and placed between tile kt's P-writes and
// P-reads. Those MFMAs have no deps on tile kt, so the scheduler fills
// the S-MFMA-latency / exp-chain / LDS-write->read stalls that caused the
// ~46% no-issue cycles. V frags are read into registers in their own
// iteration (same buffer+addresses as R13 — no new races; barrier
// structure unchanged). Static even/odd register banks (no runtime idx).
// ---------------------------------------------------------------------------
__global__ __launch_bounds__(256, 2) void attn_mfma(
    const unsigned short* __restrict__ q, const unsigned short* __restrict__ k,
    const unsigned short* __restrict__ v,
    const void* __restrict__ rk_t, const void* __restrict__ rv_t,
    unsigned short* __restrict__ aout, const int* __restrict__ flag)
{
    const bool f32m = (*flag != 0);
    const int bid = blockIdx.x;
    const int n = bid & 31, qt = bid >> 5;
    const int t0 = qt * 128;
    const int tid = threadIdx.x, w = tid >> 6, lane = tid & 63;
    const int quad = lane >> 4, lc = lane & 15;

    __shared__ unsigned short k_s[2][64 * 64];   // K[s][d] swizzled (buf0: rv^T later)
    __shared__ unsigned short v_s[2][64 * 64];   // V^T[d][s] swizzled
    __shared__ unsigned short p_s[4][32 * 72];   // per-wave P[t][s] / P_extra; rk staging
    __shared__ unsigned short qrk_s[128 * 36];   // qrk[t_local][r] bf16 (log2 dom.)
    __shared__ unsigned short diag16[128 * 33];  // e-values at |rel|<16, bf16
    __shared__ float st_L[128], st_R[128];

    const unsigned short* qn = q + ((size_t)n * T_ + t0) * D_;
    const unsigned short* kn = k + (size_t)n * T_ * D_;
    const unsigned short* vn = v + (size_t)n * D_ * T_;   // V^T [D][T]

    // Q fragments (B-operand for S^T)
    s8b qa[2][2];
    #pragma unroll
    for (int nt = 0; nt < 2; nt++)
        #pragma unroll
        for (int kf = 0; kf < 2; kf++)
            qa[nt][kf] = *(const s8b*)(qn + (size_t)(w*32 + nt*16 + lc) * D_ + kf*32 + quad*8);

    for (int i = tid; i < 128 * 33; i += 256) diag16[i] = 0;

    // stage rk (bf16, padded [48][72], rows>=33 zero) into p_s area
    unsigned int* rks = (unsigned int*)&p_s[0][0];
    for (int i = tid; i < 48 * 36; i += 256) {
        int r = i / 36, c2 = i % 36;
        unsigned int val = 0;
        if (r < 33 && c2 < 32)
            val = pk2(ld1d(rk_t, r*64 + 2*c2, f32m), ld1d(rk_t, r*64 + 2*c2 + 1, f32m));
        rks[i] = val;
    }
    __syncthreads();

    // qrk[t][r] = q[t] . rk[r] via MFMA (prologue-only)
    #pragma unroll
    for (int mt = 0; mt < 2; mt++)
        for (int nt = 0; nt < 3; nt++) {
            s8b b0 = *(const s8b*)((const unsigned short*)rks + (nt*16 + lc)*72 + quad*8);
            s8b b1 = *(const s8b*)((const unsigned short*)rks + (nt*16 + lc)*72 + 32 + quad*8);
            f4 a = (f4){0.f, 0.f, 0.f, 0.f};
            a = MFMA_B16(qa[mt][0], b0, a);
            a = MFMA_B16(qa[mt][1], b1, a);
            #pragma unroll
            for (int r = 0; r < 4; r++) {
                float nb = __shfl_xor(a[r], 1);
                int col = nt*16 + lc;
                if (!(lane & 1) && col < 34)
                    ((unsigned int*)qrk_s)[(w*32 + mt*16 + quad*4 + r)*18 + (col >> 1)] = pk2(a[r], nb);
            }
        }
    __syncthreads();   // rk staging (aliased with p_s) free after this

    // per-lane Shaw edge biases (t = w*32 + nt*16 + lc)
    float qLn[2], qRn[2];
    float L_p[2] = {0.f, 0.f}, R_p[2] = {0.f, 0.f};
    f4 O[4][2], lsN[2], lsL[2], lsR[2];
    #pragma unroll
    for (int nt = 0; nt < 2; nt++) {
        int row = w*32 + nt*16 + lc;
        qLn[nt] = bu2f(qrk_s[row*36 + 0]);
        qRn[nt] = bu2f(qrk_s[row*36 + 32]);
        lsN[nt] = (f4){0.f, 0.f, 0.f, 0.f};
        lsL[nt] = (f4){0.f, 0.f, 0.f, 0.f};
        lsR[nt] = (f4){0.f, 0.f, 0.f, 0.f};
        #pragma unroll
        for (int dt = 0; dt < 4; dt++) O[dt][nt] = (f4){0.f, 0.f, 0.f, 0.f};
    }
    const short ob = (short)0x3F80;   // bf16 1.0
    const s8b ones = { ob, ob, ob, ob, ob, ob, ob, ob };

    // staging mapping: row group w*16 + grr, source chunk xor-swizzled
    const int grr = lane >> 3;
    const int gcc = (lane & 7) ^ grr;
    const size_t koff = (size_t)(w*16 + grr) * D_ + gcc*8;   // + (s0 + j*8)*D_
    const size_t voff = (size_t)(w*16 + grr) * T_ + gcc*8;   // + j*8*T_ + s0

    // tile-0 register prefetch + write buf 0
    s8b kr0 = *(const s8b*)(kn + koff);
    s8b kr1 = *(const s8b*)(kn + koff + 8*D_);
    s8b vr0 = *(const s8b*)(vn + voff);
    s8b vr1 = *(const s8b*)(vn + voff + (size_t)8*T_);
    *(s8b*)&k_s[0][(w*128 +      lane) * 8] = kr0;
    *(s8b*)&k_s[0][(w*128 + 64 + lane) * 8] = kr1;
    *(s8b*)&v_s[0][(w*128 +      lane) * 8] = vr0;
    *(s8b*)&v_s[0][(w*128 + 64 + lane) * 8] = vr1;
    __syncthreads();

    const int lc7 = lc & 7;

    // pipeline state: even/odd banks (static indexing only)
    s8b pbA[2][2], pbB[2][2];     // P fragments held one tile
    s8b vcA[4][2], vcB[4][2];     // V fragments held one tile
    int clsA = 0, clsB = 0;       // 0 = nearT, 1 = farL, 2 = farR

    // rowsum + PV for a COMPLETED tile — register-only MFMAs, no LDS/global.
    auto pv_phase = [&](s8b (&pb)[2][2], s8b (&vc)[4][2], int cls) {
        if (cls == 0) {
            #pragma unroll
            for (int nt = 0; nt < 2; nt++) {
                lsN[nt] = MFMA_B16(ones, pb[nt][0], lsN[nt]);
                lsN[nt] = MFMA_B16(ones, pb[nt][1], lsN[nt]);
            }
        } else if (cls == 1) {
            #pragma unroll
            for (int nt = 0; nt < 2; nt++) {
                lsL[nt] = MFMA_B16(ones, pb[nt][0], lsL[nt]);
                lsL[nt] = MFMA_B16(ones, pb[nt][1], lsL[nt]);
            }
        } else {
            #pragma unroll
            for (int nt = 0; nt < 2; nt++) {
                lsR[nt] = MFMA_B16(ones, pb[nt][0], lsR[nt]);
                lsR[nt] = MFMA_B16(ones, pb[nt][1], lsR[nt]);
            }
        }
        #pragma unroll
        for (int dt = 0; dt < 4; dt++) {
            O[dt][0] = MFMA_B16(vc[dt][0], pb[0][0], O[dt][0]);
            O[dt][0] = MFMA_B16(vc[dt][1], pb[0][1], O[dt][0]);
            O[dt][1] = MFMA_B16(vc[dt][0], pb[1][0], O[dt][1]);
            O[dt][1] = MFMA_B16(vc[dt][1], pb[1][1], O[dt][1]);
        }
    };

    // one iteration: S+exp of tile kt (fills pbC/vcC/clsC), PV of tile kt-1
    // (pbP/vcP/clsP) interleaved into its stalls, then staging + barrier.
    auto body = [&](int kt, s8b (&pbC)[2][2], s8b (&vcC)[4][2], int& clsC,
                    s8b (&pbP)[2][2], s8b (&vcP)[4][2], int& clsP, bool doPV) {
        const int s0 = kt * 64;
        const int cur = kt & 1;
        if (kt + 1 < 32) {   // issue next tile's global loads now
            kr0 = *(const s8b*)(kn + koff + (size_t)(s0 + 64)*D_);
            kr1 = *(const s8b*)(kn + koff + (size_t)(s0 + 72)*D_);
            vr0 = *(const s8b*)(vn + voff + s0 + 64);
            vr1 = *(const s8b*)(vn + voff + (size_t)8*T_ + s0 + 64);
        }

        const bool farL  = (s0 + 63 < t0 - 16);
        const bool farR  = (s0 > t0 + 143);
        const bool nearT = !farL && !farR;
        clsC = nearT ? 0 : (farL ? 1 : 2);

        // K fragments (A-operand for S^T): K[s=st*16+lc][d]
        s8b ak[4][2];
        #pragma unroll
        for (int st = 0; st < 4; st++) {
            int row = st*16 + lc;
            ak[st][0] = *(const s8b*)&k_s[cur][(row*8 + (quad       ^ lc7)) * 8];
            ak[st][1] = *(const s8b*)&k_s[cur][(row*8 + ((4 + quad) ^ lc7)) * 8];
        }

        // S^T = K·Q^T (+ bias), exp2, pack b64 into P[t][s]
        #pragma unroll
        for (int st = 0; st < 4; st++)
            #pragma unroll
            for (int nt = 0; nt < 2; nt++) {
                f4 a;
                if (nearT) a = (f4){0.f, 0.f, 0.f, 0.f};
                else {
                    float qb = farL ? qLn[nt] : qRn[nt];
                    a = (f4){qb, qb, qb, qb};
                }
                a = MFMA_B16(ak[st][0], qa[nt][0], a);
                a = MFMA_B16(ak[st][1], qa[nt][1], a);
                unsigned int lo, hi;
                if (nearT) {
                    const int t_l = w*32 + nt*16 + lc;
                    const int sb  = s0 + st*16 + quad*4 - (t0 + t_l);
                    unsigned short eb[4];
                    #pragma unroll
                    for (int r = 0; r < 4; r++) {
                        int rel = sb + r;
                        int rc = rel < -16 ? -16 : (rel > 16 ? 16 : rel);
                        float e = fexp2(a[r] + bu2f(qrk_s[t_l*36 + rc + 16]));
                        eb[r] = f2bu_fast(e);
                        if (rel <= -16)      L_p[nt] += e;
                        else if (rel >= 16)  R_p[nt] += e;
                        else                 diag16[t_l*33 + rel + 15] = eb[r];
                    }
                    lo = (unsigned int)eb[0] | ((unsigned int)eb[1] << 16);
                    hi = (unsigned int)eb[2] | ((unsigned int)eb[3] << 16);
                } else {
                    lo = pk2_fast(fexp2(a[0]), fexp2(a[1]));
                    hi = pk2_fast(fexp2(a[2]), fexp2(a[3]));
                }
                *(uint2*)&p_s[w][(nt*16 + lc)*72 + st*16 + quad*4] = make_uint2(lo, hi);
            }

        // V fragments of THIS tile into registers (consumed next iteration).
        // Same buffer+addresses as R13 read in its PV step — no new races.
        #pragma unroll
        for (int dt = 0; dt < 4; dt++) {
            int row = dt*16 + lc;
            vcC[dt][0] = *(const s8b*)&v_s[cur][(row*8 + (quad       ^ lc7)) * 8];
            vcC[dt][1] = *(const s8b*)&v_s[cur][(row*8 + ((4 + quad) ^ lc7)) * 8];
        }

        // PV of the PREVIOUS tile — register-only, dependency-free w.r.t.
        // everything above; fills MFMA-latency/exp/LDS-write stalls and pads
        // the P write->read round-trip.
        if (doPV) pv_phase(pbP, vcP, clsP);

        // P fragments of THIS tile (B-operand): P[t=lc][s=quad*8+j]
        #pragma unroll
        for (int nt = 0; nt < 2; nt++) {
            pbC[nt][0] = *(const s8b*)&p_s[w][(nt*16 + lc)*72 + quad*8];
            pbC[nt][1] = *(const s8b*)&p_s[w][(nt*16 + lc)*72 + 32 + quad*8];
        }

        if (kt + 1 < 32) {   // write prefetched tile to the other buffer
            *(s8b*)&k_s[cur ^ 1][(w*128 +      lane) * 8] = kr0;
            *(s8b*)&k_s[cur ^ 1][(w*128 + 64 + lane) * 8] = kr1;
            *(s8b*)&v_s[cur ^ 1][(w*128 +      lane) * 8] = vr0;
            *(s8b*)&v_s[cur ^ 1][(w*128 + 64 + lane) * 8] = vr1;
        }
        __syncthreads();
    };

    body(0, pbA, vcA, clsA, pbB, vcB, clsB, false);
    for (int kt2 = 1; kt2 < 31; kt2 += 2) {
        body(kt2,     pbB, vcB, clsB, pbA, vcA, clsA, true);
        body(kt2 + 1, pbA, vcA, clsA, pbB, vcB, clsB, true);
    }
    body(31, pbB, vcB, clsB, pbA, vcA, clsA, true);
    pv_phase(pbB, vcB, clsB);   // drain: tile 31

    // ---- epilogue: totals, relpos-V via rv^T·P_extra^T, normalize, store ----
    float linv[2];
    #pragma unroll
    for (int nt = 0; nt < 2; nt++) {
        float l = lsN[nt][0] + lsL[nt][0] + lsR[nt][0];
        float L = lsL[nt][0] + qsumq(L_p[nt]);
        float R = lsR[nt][0] + qsumq(R_p[nt]);
        linv[nt] = 1.f / l;
        if (quad == 0) {
            int row = w*32 + nt*16 + lc;
            st_L[row] = L; st_R[row] = R;
        }
    }
    // stage rv TRANSPOSED into k_s[0] with the SAME xor swizzle (r>=33 zero)
    {
        unsigned int* rvs = (unsigned int*)&k_s[0][0];
        for (int i = tid; i < 64 * 32; i += 256) {
            int d = i >> 5, dwL = i & 31;
            int r0 = dwL * 2, r1 = r0 + 1;
            float x0 = (r0 < 33) ? ld1d(rv_t, (size_t)r0 * 64 + d, f32m) : 0.f;
            float x1 = (r1 < 33) ? ld1d(rv_t, (size_t)r1 * 64 + d, f32m) : 0.f;
            int phys = d * 32 + ((dwL >> 2) ^ (d & 7)) * 4 + (dwL & 3);
            rvs[phys] = pk2(x0, x1);
        }
    }
    __syncthreads();
    // build P_extra[32][64] bf16 in own wave region (cols 33..63 = 0)
    for (int j = 0; j < 32; j++) {
        int c = lane;
        int row = w*32 + j;
        unsigned short pv;
        if (c == 0)        pv = f2bu(st_L[row]);
        else if (c == 32)  pv = f2bu(st_R[row]);
        else if (c < 32)   pv = diag16[row*33 + c - 1];
        else               pv = 0;
        p_s[w][j*72 + c] = pv;
    }
    // O^T += rv^T · P_extra^T
    s8b pe[2][2];
    #pragma unroll
    for (int nt = 0; nt < 2; nt++) {
        pe[nt][0] = *(const s8b*)&p_s[w][(nt*16 + lc)*72 + quad*8];
        pe[nt][1] = *(const s8b*)&p_s[w][(nt*16 + lc)*72 + 32 + quad*8];
    }
    #pragma unroll
    for (int dt = 0; dt < 4; dt++) {
        int row = dt*16 + lc;
        s8b a0 = *(const s8b*)&k_s[0][(row*8 + (quad       ^ lc7)) * 8];
        s8b a1 = *(const s8b*)&k_s[0][(row*8 + ((4 + quad) ^ lc7)) * 8];
        O[dt][0] = MFMA_B16(a0, pe[0][0], O[dt][0]);
        O[dt][0] = MFMA_B16(a1, pe[0][1], O[dt][0]);
        O[dt][1] = MFMA_B16(a0, pe[1][0], O[dt][1]);
        O[dt][1] = MFMA_B16(a1, pe[1][1], O[dt][1]);
    }
    // normalize + store bf16 [T][B][E] — packed 8B store, no shfl
    const int bb = n >> 4, h = n & 15;
    #pragma unroll
    for (int nt = 0; nt < 2; nt++) {
        int t_g = t0 + w*32 + nt*16 + lc;
        #pragma unroll
        for (int dt = 0; dt < 4; dt++) {
            float v0 = O[dt][nt][0] * linv[nt];
            float v1 = O[dt][nt][1] * linv[nt];
            float v2 = O[dt][nt][2] * linv[nt];
            float v3 = O[dt][nt][3] * linv[nt];
            int e = h*64 + dt*16 + quad*4;
            *(uint2*)&aout[((size_t)t_g * B_ + bb) * E_ + e] =
                make_uint2(pk2(v0, v1), pk2(v2, v3));
        }
    }
}

// ---------------------------------------------------------------------------
// Output projection, bf16 MFMA GEMM, XCD swizzle, glds staging, dbuf.
// ---------------------------------------------------------------------------
__global__ __launch_bounds__(256, 3) void out_gemm(
    const unsigned short* __restrict__ A,
    const unsigned short* __restrict__ Wob, const unsigned short* __restrict__ bob,
    void* __restrict__ out, const int* __restrict__ flag)
{
    const bool f32m = (*flag != 0);
    const int bid = blockIdx.x;            // 256 blocks
    const int r_ = bid & 7, s_ = bid >> 3;
    const int g = r_ + 8 * (s_ >> 3);
    const int m0 = g * 128;
    const int e0 = (s_ & 7) * 128;

    const int tid = threadIdx.x, w = tid >> 6, lane = tid & 63;
    const int quad = lane >> 4, lc = lane & 15;
    const int wx = w & 1, wy = w >> 1;

    __shared__ unsigned short a_s[2][128 * 32];
    __shared__ unsigned short b_s[2][128 * 32];

    f4 acc[4][4];
    #pragma unroll
    for (int i = 0; i < 4; i++)
        #pragma unroll
        for (int j = 0; j < 4; j++) acc[i][j] = (f4){0.f, 0.f, 0.f, 0.f};

    const int gr = lane >> 2;
    const int gc = (lane & 3) ^ ((lane >> 2) & 3);
    const size_t aoff = (size_t)(m0 + w*32 + gr) * E_ + gc*8;
    const size_t boff = (size_t)(e0 + w*32 + gr) * E_ + gc*8;

    #pragma unroll
    for (int j = 0; j < 2; j++) {
        glds16(A   + aoff + (size_t)j*16*E_, &a_s[0][(w*128 + j*64) * 8]);
        glds16(Wob + boff + (size_t)j*16*E_, &b_s[0][(w*128 + j*64) * 8]);
    }
    __syncthreads();

    const int fcA = quad ^ (lc & 3);
    for (int k0 = 0; k0 < E_; k0 += 32) {
        const int cur = (k0 >> 5) & 1;
        if (k0 + 32 < E_) {
            #pragma unroll
            for (int j = 0; j < 2; j++) {
                glds16(A   + aoff + (size_t)j*16*E_ + k0 + 32, &a_s[cur^1][(w*128 + j*64) * 8]);
                glds16(Wob + boff + (size_t)j*16*E_ + k0 + 32, &b_s[cur^1][(w*128 + j*64) * 8]);
            }
        }
        s8b af[4], bfr[4];
        #pragma unroll
        for (int i = 0; i < 4; i++)
            af[i]  = *(const s8b*)&a_s[cur][((wy*64 + i*16 + lc)*4 + fcA) * 8];
        #pragma unroll
        for (int i = 0; i < 4; i++)
            bfr[i] = *(const s8b*)&b_s[cur][((wx*64 + i*16 + lc)*4 + fcA) * 8];
        #pragma unroll
        for (int ms = 0; ms < 4; ms++)
            #pragma unroll
            for (int ns = 0; ns < 4; ns++)
                acc[ms][ns] = MFMA_B16(af[ms], bfr[ns], acc[ms][ns]);
        __syncthreads();
    }

    float bias_v[4];
    #pragma unroll
    for (int ns = 0; ns < 4; ns++) bias_v[ns] = bu2f(bob[e0 + wx*64 + ns*16 + lc]);

    #pragma unroll
    for (int ms = 0; ms < 4; ms++)
        #pragma unroll
        for (int ns = 0; ns < 4; ns++)
            #pragma unroll
            for (int r2 = 0; r2 < 4; r2++) {
                float val = acc[ms][ns][r2] + bias_v[ns];
                size_t m = m0 + wy*64 + ms*16 + quad*4 + r2;
                int e = e0 + wx*64 + ns*16 + lc;
                if (f32m) {
                    ((float*)out)[m * E_ + e] = val;
                } else {
                    float nb = __shfl_xor(val, 1);
                    if (!(lane & 1))
                        *(unsigned int*)&((unsigned short*)out)[m * E_ + e] = pk2(val, nb);
                }
            }
}

extern "C" void kernel_launch(void* const* d_in, const int* in_sizes, int n_in,
                              void* d_out, int out_size, void* d_ws, size_t ws_size,
                              hipStream_t stream) {
    const void* x  = d_in[0];
    const void* Wq = d_in[1];  const void* bq = d_in[2];
    const void* Wk = d_in[3];  const void* bk = d_in[4];
    const void* Wv = d_in[5];  const void* bv = d_in[6];
    const void* Wo = d_in[7];  const void* bo = d_in[8];
    const void* rk = d_in[9];  const void* rv = d_in[10];

    int* flag = (int*)d_ws;
    const size_t HTD = (size_t)NH_ * T_ * D_;        // 4,194,304 elems
    unsigned short* qw = (unsigned short*)((char*)d_ws + 256);
    unsigned short* kw = qw + HTD;
    unsigned short* vw = kw + HTD;                   // V^T [N][D][T] bf16
    unsigned short* aw = vw + HTD;                   // [4096][1024] bf16 pre-Wo
    unsigned short* xw = aw + (size_t)M_ * E_;       // x as bf16 (8 MB)
    unsigned short* Ww = xw + (size_t)M_ * E_;       // Wq,Wk,Wv,Wo bf16 (8 MB)
    unsigned short* bw = Ww + (size_t)4 * E_ * E_;   // bq,bk,bv,bo bf16 (8 KB)
    // ws use: ~48 MB

    cvt_bf16<<<dim3((M_*E_/8 + 255)/256, 9), 256, 0, stream>>>(
        x, Wq, Wk, Wv, Wo, bq, bk, bv, bo, xw, Ww, bw, flag);
    qkv_gemm<<<dim3(768), 256, 0, stream>>>(xw, Ww, bw, qw, kw, vw);
    attn_mfma<<<dim3(NH_ * (T_/128)), 256, 0, stream>>>(qw, kw, vw, rk, rv, aw, flag);
    out_gemm<<<dim3(256), 256, 0, stream>>>(aw, Ww + (size_t)3*E_*E_, bw + 3*E_,
                                            d_out, flag);
}

// Round 7
// 221.175 us; speedup vs baseline: 1.3538x; 1.0655x over previous
//
#include <hip/hip_runtime.h>
#include <hip/hip_bf16.h>
#include <math.h>

#define T_   2048
#define B_   2
#define E_   1024
#define H_   16
#define D_   64
#define NH_  32
#define M_   4096

typedef __attribute__((ext_vector_type(8))) short s8b;   // 8 bf16 (4 VGPRs)
typedef __attribute__((ext_vector_type(4))) float f4;    // 4 f32 acc

#define MFMA_B16(a,b,c) __builtin_amdgcn_mfma_f32_16x16x32_bf16(a,b,c,0,0,0)
#define LOG2E 1.44269504088896f

__device__ __forceinline__ unsigned short f2bu(float f) {
    union { __hip_bfloat16 h; unsigned short u; } cv;
    cv.h = __float2bfloat16(f);
    return cv.u;
}
// fast bf16: round-half-up truncation (positive finite values) — 2 VALU ops
__device__ __forceinline__ unsigned short f2bu_fast(float f) {
    return (unsigned short)((__float_as_uint(f) + 0x8000u) >> 16);
}
__device__ __forceinline__ float bu2f(unsigned short u) {
    union { __hip_bfloat16 h; unsigned short u; } cv; cv.u = u;
    return __bfloat162float(cv.h);
}
__device__ __forceinline__ unsigned int pk2(float a, float b) {
    return (unsigned int)f2bu(a) | ((unsigned int)f2bu(b) << 16);
}
// pack two f32 -> packed bf16 pair with round-half-up (cheap)
__device__ __forceinline__ unsigned int pk2_fast(float a, float b) {
    return ((__float_as_uint(a) + 0x8000u) >> 16) |
           ((__float_as_uint(b) + 0x8000u) & 0xFFFF0000u);
}
// raw v_exp_f32 — exp2f() without fast-math expands to a denorm-guard
// sequence (~12 extra VALU ops); attention scores never reach denormals.
__device__ __forceinline__ float fexp2(float x) {
    return __builtin_amdgcn_exp2f(x);
}
__device__ __forceinline__ float ld1d(const void* p, size_t idx, bool f32) {
    return f32 ? ((const float*)p)[idx] : bu2f(((const unsigned short*)p)[idx]);
}
// sum across the 4 quads (lane bits 4-5)
__device__ __forceinline__ float qsumq(float v) {
    v += __shfl_xor(v, 16); v += __shfl_xor(v, 32);
    return v;
}
// async global->LDS, 16 B per lane (GEMMs only — attn uses register prefetch
// because its per-tile barrier drains vmcnt(0) and exposes the DMA latency)
__device__ __forceinline__ void glds16(const unsigned short* g, unsigned short* l) {
    __builtin_amdgcn_global_load_lds(
        (const __attribute__((address_space(1))) unsigned int*)g,
        (__attribute__((address_space(3))) unsigned int*)l, 16, 0, 0);
}
// dtype detect, wave-local (identical result in every wave): sample 64 u16
// words of x; bf16 data -> ~all exponent fields sane; f32-as-u16 -> ~half.
__device__ __forceinline__ bool detect_f32(const unsigned short* q16) {
    int e = (q16[threadIdx.x & 63] >> 7) & 0xFF;
    bool sane = (e == 0) || (e >= 97 && e <= 157);
    unsigned long long m = __ballot(sane);
    return __popcll(m) < 56;   // true = f32 inputs
}

// ---------------------------------------------------------------------------
// One-pass f32->bf16 conversion of x, Wq..Wo, bq..bo into ws. Also publishes
// the dtype flag (block (0,0) of the x region) for the attn/out kernels.
// ---------------------------------------------------------------------------
__global__ __launch_bounds__(256) void cvt_bf16(
    const void* __restrict__ x,
    const void* __restrict__ Wq, const void* __restrict__ Wk,
    const void* __restrict__ Wv, const void* __restrict__ Wo,
    const void* __restrict__ bq, const void* __restrict__ bk,
    const void* __restrict__ bv, const void* __restrict__ bo,
    unsigned short* __restrict__ xw, unsigned short* __restrict__ Ww,
    unsigned short* __restrict__ bw, int* __restrict__ flag)
{
    const bool f32m = detect_f32((const unsigned short*)x);
    if (blockIdx.x == 0 && blockIdx.y == 0 && threadIdx.x == 0)
        *flag = f32m ? 1 : 0;
    const int y = blockIdx.y;
    const void* src; unsigned short* dst; int n;
    if (y == 0)      { src = x; dst = xw; n = M_ * E_; }
    else if (y <= 4) {
        src = (y == 1) ? Wq : (y == 2) ? Wk : (y == 3) ? Wv : Wo;
        dst = Ww + (size_t)(y - 1) * E_ * E_; n = E_ * E_;
    } else {
        src = (y == 5) ? bq : (y == 6) ? bk : (y == 7) ? bv : bo;
        dst = bw + (size_t)(y - 5) * E_; n = E_;
    }
    int i = (blockIdx.x * 256 + threadIdx.x) * 8;
    if (i >= n) return;
    if (f32m) {
        const float* s = (const float*)src + i;
        float4 f0 = *(const float4*)s, f1 = *(const float4*)(s + 4);
        union { unsigned int d[4]; s8b v; } u;
        u.d[0] = pk2(f0.x, f0.y); u.d[1] = pk2(f0.z, f0.w);
        u.d[2] = pk2(f1.x, f1.y); u.d[3] = pk2(f1.z, f1.w);
        *(s8b*)(dst + i) = u.v;
    } else {
        *(s8b*)(dst + i) = *(const s8b*)((const unsigned short*)src + i);
    }
}

// ---------------------------------------------------------------------------
// QKV projection, bf16 MFMA GEMM, XCD swizzle, glds staging (xor-swizzled),
// double-buffered single-barrier. p==2 (V) is written TRANSPOSED [N][D][T].
// ---------------------------------------------------------------------------
__global__ __launch_bounds__(256, 3) void qkv_gemm(
    const unsigned short* __restrict__ xw, const unsigned short* __restrict__ Ww,
    const unsigned short* __restrict__ bw,
    unsigned short* __restrict__ qo, unsigned short* __restrict__ ko,
    unsigned short* __restrict__ vo)
{
    const int bid = blockIdx.x;            // 768 blocks
    const int r_ = bid & 7, s_ = bid >> 3;
    const int g = r_ + 8 * (s_ >> 3);      // group in [0,96): (m,p)
    const int e0 = (s_ & 7) * 128;
    const int m0 = (g & 31) * 128;
    const int p  = g >> 5;
    const unsigned short* W    = Ww + (size_t)p * E_ * E_;
    const unsigned short* bias = bw + (size_t)p * E_;
    const float scale = (p == 0) ? 0.125f * LOG2E : 1.0f;

    const int tid = threadIdx.x, w = tid >> 6, lane = tid & 63;
    const int quad = lane >> 4, lc = lane & 15;
    const int wx = w & 1, wy = w >> 1;

    __shared__ unsigned short a_s[2][128 * 32];
    __shared__ unsigned short b_s[2][128 * 32];

    f4 acc[4][4];
    #pragma unroll
    for (int i = 0; i < 4; i++)
        #pragma unroll
        for (int j = 0; j < 4; j++) acc[i][j] = (f4){0.f, 0.f, 0.f, 0.f};

    const int gr = lane >> 2;
    const int gc = (lane & 3) ^ ((lane >> 2) & 3);
    const size_t aoff = (size_t)(m0 + w*32 + gr) * E_ + gc*8;
    const size_t boff = (size_t)(e0 + w*32 + gr) * E_ + gc*8;

    #pragma unroll
    for (int j = 0; j < 2; j++) {
        glds16(xw + aoff + (size_t)j*16*E_, &a_s[0][(w*128 + j*64) * 8]);
        glds16(W  + boff + (size_t)j*16*E_, &b_s[0][(w*128 + j*64) * 8]);
    }
    __syncthreads();

    const int fcA = quad ^ (lc & 3);
    for (int k0 = 0; k0 < E_; k0 += 32) {
        const int cur = (k0 >> 5) & 1;
        if (k0 + 32 < E_) {
            #pragma unroll
            for (int j = 0; j < 2; j++) {
                glds16(xw + aoff + (size_t)j*16*E_ + k0 + 32, &a_s[cur^1][(w*128 + j*64) * 8]);
                glds16(W  + boff + (size_t)j*16*E_ + k0 + 32, &b_s[cur^1][(w*128 + j*64) * 8]);
            }
        }
        s8b af[4], bfr[4];
        #pragma unroll
        for (int i = 0; i < 4; i++)
            af[i]  = *(const s8b*)&a_s[cur][((wy*64 + i*16 + lc)*4 + fcA) * 8];
        #pragma unroll
        for (int i = 0; i < 4; i++)
            bfr[i] = *(const s8b*)&b_s[cur][((wx*64 + i*16 + lc)*4 + fcA) * 8];
        #pragma unroll
        for (int ms = 0; ms < 4; ms++)
            #pragma unroll
            for (int ns = 0; ns < 4; ns++)
                acc[ms][ns] = MFMA_B16(af[ms], bfr[ns], acc[ms][ns]);
        __syncthreads();
    }

    float bias_v[4];
    #pragma unroll
    for (int ns = 0; ns < 4; ns++) bias_v[ns] = bu2f(bias[e0 + wx*64 + ns*16 + lc]);

    if (p < 2) {
        #pragma unroll
        for (int ms = 0; ms < 4; ms++)
            #pragma unroll
            for (int ns = 0; ns < 4; ns++)
                #pragma unroll
                for (int r2 = 0; r2 < 4; r2++) {
                    float val = (acc[ms][ns][r2] + bias_v[ns]) * scale;
                    float nb = __shfl_xor(val, 1);
                    if (!(lane & 1)) {
                        int m = m0 + wy*64 + ms*16 + quad*4 + r2;
                        int t = m >> 1, bb = m & 1;
                        int e = e0 + wx*64 + ns*16 + lc;
                        int h = e >> 6, d = e & 63;
                        unsigned short* dst = (p == 0) ? qo : ko;
                        *(unsigned int*)&dst[(((size_t)(bb*H_ + h) * T_ + t) << 6) + d] = pk2(val, nb);
                    }
                }
    } else {
        // V transposed: vo[nh][d][t]
        #pragma unroll
        for (int ms = 0; ms < 4; ms++) {
            int t0v = (m0 + wy*64 + ms*16 + quad*4) >> 1;
            #pragma unroll
            for (int ns = 0; ns < 4; ns++) {
                int e = e0 + wx*64 + ns*16 + lc;
                int h = e >> 6, d = e & 63;
                float v0 = acc[ms][ns][0] + bias_v[ns];
                float v1 = acc[ms][ns][1] + bias_v[ns];
                float v2 = acc[ms][ns][2] + bias_v[ns];
                float v3 = acc[ms][ns][3] + bias_v[ns];
                *(unsigned int*)&vo[((size_t)h        * 64 + d) * T_ + t0v] = pk2(v0, v2);
                *(unsigned int*)&vo[((size_t)(H_ + h) * 64 + d) * T_ + t0v] = pk2(v1, v3);
            }
        }
    }
}

// ---------------------------------------------------------------------------
// Flash attention with Shaw bias — R17: 8-wave blocks (512 thr), same
// per-block geometry as R13 (128 Q-rows, KVBLK=64, dbuf K/V, ONE barrier
// per tile, 70 KB LDS). Evidence: R14 (smaller tiles), R15 (no staging),
// R16 (PV defer) all failed/neutral -> per-tile cost is pinned by too few
// independent streams (2 waves/SIMD, phase-locked blocks). This splits the
// SAME block work across 8 waves x 16 Q-rows: staging traffic, barrier
// count, LDS, MFMA totals unchanged; waves/SIMD doubles to 4. Per-wave
// state halves -> VGPR < 128 (launch_bounds(512,4) = 2 blocks/CU).
// ---------------------------------------------------------------------------
__global__ __launch_bounds__(512, 4) void attn_mfma(
    const unsigned short* __restrict__ q, const unsigned short* __restrict__ k,
    const unsigned short* __restrict__ v,
    const void* __restrict__ rk_t, const void* __restrict__ rv_t,
    unsigned short* __restrict__ aout, const int* __restrict__ flag)
{
    const bool f32m = (*flag != 0);
    const int bid = blockIdx.x;
    const int n = bid & 31, qt = bid >> 5;
    const int t0 = qt * 128;
    const int tid = threadIdx.x, w = tid >> 6, lane = tid & 63;
    const int quad = lane >> 4, lc = lane & 15;

    __shared__ unsigned short k_s[2][64 * 64];   // K[s][d] swizzled (buf0: rv^T later)
    __shared__ unsigned short v_s[2][64 * 64];   // V^T[d][s] swizzled
    __shared__ unsigned short p_s[8][16 * 72];   // per-wave P[t][s] / P_extra; rk staging
    __shared__ unsigned short qrk_s[128 * 36];   // qrk[t_local][r] bf16 (log2 dom.)
    __shared__ unsigned short diag16[128 * 33];  // e-values at |rel|<16, bf16
    __shared__ float st_L[128], st_R[128];

    const unsigned short* qn = q + ((size_t)n * T_ + t0) * D_;
    const unsigned short* kn = k + (size_t)n * T_ * D_;
    const unsigned short* vn = v + (size_t)n * D_ * T_;   // V^T [D][T]

    // Q fragments (B-operand for S^T): 16 rows per wave (t = w*16 + lc)
    s8b qa[2];
    #pragma unroll
    for (int kf = 0; kf < 2; kf++)
        qa[kf] = *(const s8b*)(qn + (size_t)(w*16 + lc) * D_ + kf*32 + quad*8);

    for (int i = tid; i < 128 * 33; i += 512) diag16[i] = 0;

    // stage rk (bf16, padded [48][72], rows>=33 zero) into p_s area
    unsigned int* rks = (unsigned int*)&p_s[0][0];
    for (int i = tid; i < 48 * 36; i += 512) {
        int r = i / 36, c2 = i % 36;
        unsigned int val = 0;
        if (r < 33 && c2 < 32)
            val = pk2(ld1d(rk_t, r*64 + 2*c2, f32m), ld1d(rk_t, r*64 + 2*c2 + 1, f32m));
        rks[i] = val;
    }
    __syncthreads();

    // qrk[t][r] = q[t] . rk[r] via MFMA (prologue-only); rows w*16..w*16+15
    for (int nt = 0; nt < 3; nt++) {
        s8b b0 = *(const s8b*)((const unsigned short*)rks + (nt*16 + lc)*72 + quad*8);
        s8b b1 = *(const s8b*)((const unsigned short*)rks + (nt*16 + lc)*72 + 32 + quad*8);
        f4 a = (f4){0.f, 0.f, 0.f, 0.f};
        a = MFMA_B16(qa[0], b0, a);
        a = MFMA_B16(qa[1], b1, a);
        #pragma unroll
        for (int r = 0; r < 4; r++) {
            float nb = __shfl_xor(a[r], 1);
            int col = nt*16 + lc;
            if (!(lane & 1) && col < 34)
                ((unsigned int*)qrk_s)[(w*16 + quad*4 + r)*18 + (col >> 1)] = pk2(a[r], nb);
        }
    }
    __syncthreads();   // rk staging (aliased with p_s) free after this

    // per-lane Shaw edge biases (t = w*16 + lc)
    const int t_l = w*16 + lc;
    const float qLn = bu2f(qrk_s[t_l*36 + 0]);
    const float qRn = bu2f(qrk_s[t_l*36 + 32]);
    float L_p = 0.f, R_p = 0.f;
    f4 O[4], lsN, lsL, lsR;
    lsN = (f4){0.f, 0.f, 0.f, 0.f};
    lsL = (f4){0.f, 0.f, 0.f, 0.f};
    lsR = (f4){0.f, 0.f, 0.f, 0.f};
    #pragma unroll
    for (int dt = 0; dt < 4; dt++) O[dt] = (f4){0.f, 0.f, 0.f, 0.f};
    const short ob = (short)0x3F80;   // bf16 1.0
    const s8b ones = { ob, ob, ob, ob, ob, ob, ob, ob };

    // staging mapping: 512 threads cover the 64x64 tile in ONE 16B/thread
    // round. row = w*8 + grr, source chunk xor-swizzled: phys = src ^ (row&7).
    const int grr = lane >> 3;
    const int gcc = (lane & 7) ^ grr;
    const size_t koff = (size_t)(w*8 + grr) * D_ + gcc*8;   // + (s0)*D_
    const size_t voff = (size_t)(w*8 + grr) * T_ + gcc*8;   // + s0

    // tile-0 register prefetch + write buf 0
    s8b kr0 = *(const s8b*)(kn + koff);
    s8b vr0 = *(const s8b*)(vn + voff);
    *(s8b*)&k_s[0][(w*64 + lane) * 8] = kr0;
    *(s8b*)&v_s[0][(w*64 + lane) * 8] = vr0;
    __syncthreads();

    const int lc7 = lc & 7;
    for (int kt = 0; kt < 32; kt++) {
        const int s0 = kt * 64;
        const int cur = kt & 1;
        if (kt + 1 < 32) {   // issue next tile's global loads now
            kr0 = *(const s8b*)(kn + koff + (size_t)(s0 + 64)*D_);
            vr0 = *(const s8b*)(vn + voff + s0 + 64);
        }

        const bool farL  = (s0 + 63 < t0 - 16);
        const bool farR  = (s0 > t0 + 143);
        const bool nearT = !farL && !farR;

        // K fragments (A-operand for S^T): K[s=st*16+lc][d]
        s8b ak[4][2];
        #pragma unroll
        for (int st = 0; st < 4; st++) {
            int row = st*16 + lc;
            ak[st][0] = *(const s8b*)&k_s[cur][(row*8 + (quad       ^ lc7)) * 8];
            ak[st][1] = *(const s8b*)&k_s[cur][(row*8 + ((4 + quad) ^ lc7)) * 8];
        }

        // S^T = K·Q^T (+ bias), exp2, pack b64 into P[t][s]
        #pragma unroll
        for (int st = 0; st < 4; st++) {
            f4 a;
            if (nearT) a = (f4){0.f, 0.f, 0.f, 0.f};
            else {
                float qb = farL ? qLn : qRn;
                a = (f4){qb, qb, qb, qb};
            }
            a = MFMA_B16(ak[st][0], qa[0], a);
            a = MFMA_B16(ak[st][1], qa[1], a);
            unsigned int lo, hi;
            if (nearT) {
                const int sb = s0 + st*16 + quad*4 - (t0 + t_l);
                unsigned short eb[4];
                #pragma unroll
                for (int r = 0; r < 4; r++) {
                    int rel = sb + r;
                    int rc = rel < -16 ? -16 : (rel > 16 ? 16 : rel);
                    float e = fexp2(a[r] + bu2f(qrk_s[t_l*36 + rc + 16]));
                    eb[r] = f2bu_fast(e);
                    if (rel <= -16)      L_p += e;
                    else if (rel >= 16)  R_p += e;
                    else                 diag16[t_l*33 + rel + 15] = eb[r];
                }
                lo = (unsigned int)eb[0] | ((unsigned int)eb[1] << 16);
                hi = (unsigned int)eb[2] | ((unsigned int)eb[3] << 16);
            } else {
                lo = pk2_fast(fexp2(a[0]), fexp2(a[1]));
                hi = pk2_fast(fexp2(a[2]), fexp2(a[3]));
            }
            *(uint2*)&p_s[w][lc*72 + st*16 + quad*4] = make_uint2(lo, hi);
        }

        // P fragments (B-operand): P[t=lc][s=quad*8+j]
        s8b pb[2];
        pb[0] = *(const s8b*)&p_s[w][lc*72 + quad*8];
        pb[1] = *(const s8b*)&p_s[w][lc*72 + 32 + quad*8];
        // column sums of P^T (= row sums of P) via ones-MFMA
        if (nearT) {
            lsN = MFMA_B16(ones, pb[0], lsN);
            lsN = MFMA_B16(ones, pb[1], lsN);
        } else if (farL) {
            lsL = MFMA_B16(ones, pb[0], lsL);
            lsL = MFMA_B16(ones, pb[1], lsL);
        } else {
            lsR = MFMA_B16(ones, pb[0], lsR);
            lsR = MFMA_B16(ones, pb[1], lsR);
        }
        // O^T += V^T · P^T
        #pragma unroll
        for (int dt = 0; dt < 4; dt++) {
            int row = dt*16 + lc;
            s8b a0 = *(const s8b*)&v_s[cur][(row*8 + (quad       ^ lc7)) * 8];
            s8b a1 = *(const s8b*)&v_s[cur][(row*8 + ((4 + quad) ^ lc7)) * 8];
            O[dt] = MFMA_B16(a0, pb[0], O[dt]);
            O[dt] = MFMA_B16(a1, pb[1], O[dt]);
        }

        if (kt + 1 < 32) {   // write prefetched tile to the other buffer
            *(s8b*)&k_s[cur ^ 1][(w*64 + lane) * 8] = kr0;
            *(s8b*)&v_s[cur ^ 1][(w*64 + lane) * 8] = vr0;
        }
        __syncthreads();
    }

    // ---- epilogue: totals, relpos-V via rv^T·P_extra^T, normalize, store ----
    float l = lsN[0] + lsL[0] + lsR[0];
    float L = lsL[0] + qsumq(L_p);
    float R = lsR[0] + qsumq(R_p);
    const float linv = 1.f / l;
    if (quad == 0) { st_L[t_l] = L; st_R[t_l] = R; }
    // stage rv TRANSPOSED into k_s[0] with the SAME xor swizzle (r>=33 zero)
    {
        unsigned int* rvs = (unsigned int*)&k_s[0][0];
        for (int i = tid; i < 64 * 32; i += 512) {
            int d = i >> 5, dwL = i & 31;
            int r0 = dwL * 2, r1 = r0 + 1;
            float x0 = (r0 < 33) ? ld1d(rv_t, (size_t)r0 * 64 + d, f32m) : 0.f;
            float x1 = (r1 < 33) ? ld1d(rv_t, (size_t)r1 * 64 + d, f32m) : 0.f;
            int phys = d * 32 + ((dwL >> 2) ^ (d & 7)) * 4 + (dwL & 3);
            rvs[phys] = pk2(x0, x1);
        }
    }
    __syncthreads();
    // build P_extra[16][64] bf16 in own wave region (cols 33..63 = 0)
    for (int j = 0; j < 16; j++) {
        int c = lane;
        int row = w*16 + j;
        unsigned short pv;
        if (c == 0)        pv = f2bu(st_L[row]);
        else if (c == 32)  pv = f2bu(st_R[row]);
        else if (c < 32)   pv = diag16[row*33 + c - 1];
        else               pv = 0;
        p_s[w][j*72 + c] = pv;
    }
    // O^T += rv^T · P_extra^T
    s8b pe[2];
    pe[0] = *(const s8b*)&p_s[w][lc*72 + quad*8];
    pe[1] = *(const s8b*)&p_s[w][lc*72 + 32 + quad*8];
    #pragma unroll
    for (int dt = 0; dt < 4; dt++) {
        int row = dt*16 + lc;
        s8b a0 = *(const s8b*)&k_s[0][(row*8 + (quad       ^ lc7)) * 8];
        s8b a1 = *(const s8b*)&k_s[0][(row*8 + ((4 + quad) ^ lc7)) * 8];
        O[dt] = MFMA_B16(a0, pe[0], O[dt]);
        O[dt] = MFMA_B16(a1, pe[1], O[dt]);
    }
    // normalize + store bf16 [T][B][E] — packed 8B store, no shfl
    const int bb = n >> 4, h = n & 15;
    {
        int t_g = t0 + t_l;
        #pragma unroll
        for (int dt = 0; dt < 4; dt++) {
            float v0 = O[dt][0] * linv;
            float v1 = O[dt][1] * linv;
            float v2 = O[dt][2] * linv;
            float v3 = O[dt][3] * linv;
            int e = h*64 + dt*16 + quad*4;
            *(uint2*)&aout[((size_t)t_g * B_ + bb) * E_ + e] =
                make_uint2(pk2(v0, v1), pk2(v2, v3));
        }
    }
}

// ---------------------------------------------------------------------------
// Output projection, bf16 MFMA GEMM, XCD swizzle, glds staging, dbuf.
// ---------------------------------------------------------------------------
__global__ __launch_bounds__(256, 3) void out_gemm(
    const unsigned short* __restrict__ A,
    const unsigned short* __restrict__ Wob, const unsigned short* __restrict__ bob,
    void* __restrict__ out, const int* __restrict__ flag)
{
    const bool f32m = (*flag != 0);
    const int bid = blockIdx.x;            // 256 blocks
    const int r_ = bid & 7, s_ = bid >> 3;
    const int g = r_ + 8 * (s_ >> 3);
    const int m0 = g * 128;
    const int e0 = (s_ & 7) * 128;

    const int tid = threadIdx.x, w = tid >> 6, lane = tid & 63;
    const int quad = lane >> 4, lc = lane & 15;
    const int wx = w & 1, wy = w >> 1;

    __shared__ unsigned short a_s[2][128 * 32];
    __shared__ unsigned short b_s[2][128 * 32];

    f4 acc[4][4];
    #pragma unroll
    for (int i = 0; i < 4; i++)
        #pragma unroll
        for (int j = 0; j < 4; j++) acc[i][j] = (f4){0.f, 0.f, 0.f, 0.f};

    const int gr = lane >> 2;
    const int gc = (lane & 3) ^ ((lane >> 2) & 3);
    const size_t aoff = (size_t)(m0 + w*32 + gr) * E_ + gc*8;
    const size_t boff = (size_t)(e0 + w*32 + gr) * E_ + gc*8;

    #pragma unroll
    for (int j = 0; j < 2; j++) {
        glds16(A   + aoff + (size_t)j*16*E_, &a_s[0][(w*128 + j*64) * 8]);
        glds16(Wob + boff + (size_t)j*16*E_, &b_s[0][(w*128 + j*64) * 8]);
    }
    __syncthreads();

    const int fcA = quad ^ (lc & 3);
    for (int k0 = 0; k0 < E_; k0 += 32) {
        const int cur = (k0 >> 5) & 1;
        if (k0 + 32 < E_) {
            #pragma unroll
            for (int j = 0; j < 2; j++) {
                glds16(A   + aoff + (size_t)j*16*E_ + k0 + 32, &a_s[cur^1][(w*128 + j*64) * 8]);
                glds16(Wob + boff + (size_t)j*16*E_ + k0 + 32, &b_s[cur^1][(w*128 + j*64) * 8]);
            }
        }
        s8b af[4], bfr[4];
        #pragma unroll
        for (int i = 0; i < 4; i++)
            af[i]  = *(const s8b*)&a_s[cur][((wy*64 + i*16 + lc)*4 + fcA) * 8];
        #pragma unroll
        for (int i = 0; i < 4; i++)
            bfr[i] = *(const s8b*)&b_s[cur][((wx*64 + i*16 + lc)*4 + fcA) * 8];
        #pragma unroll
        for (int ms = 0; ms < 4; ms++)
            #pragma unroll
            for (int ns = 0; ns < 4; ns++)
                acc[ms][ns] = MFMA_B16(af[ms], bfr[ns], acc[ms][ns]);
        __syncthreads();
    }

    float bias_v[4];
    #pragma unroll
    for (int ns = 0; ns < 4; ns++) bias_v[ns] = bu2f(bob[e0 + wx*64 + ns*16 + lc]);

    #pragma unroll
    for (int ms = 0; ms < 4; ms++)
        #pragma unroll
        for (int ns = 0; ns < 4; ns++)
            #pragma unroll
            for (int r2 = 0; r2 < 4; r2++) {
                float val = acc[ms][ns][r2] + bias_v[ns];
                size_t m = m0 + wy*64 + ms*16 + quad*4 + r2;
                int e = e0 + wx*64 + ns*16 + lc;
                if (f32m) {
                    ((float*)out)[m * E_ + e] = val;
                } else {
                    float nb = __shfl_xor(val, 1);
                    if (!(lane & 1))
                        *(unsigned int*)&((unsigned short*)out)[m * E_ + e] = pk2(val, nb);
                }
            }
}

extern "C" void kernel_launch(void* const* d_in, const int* in_sizes, int n_in,
                              void* d_out, int out_size, void* d_ws, size_t ws_size,
                              hipStream_t stream) {
    const void* x  = d_in[0];
    const void* Wq = d_in[1];  const void* bq = d_in[2];
    const void* Wk = d_in[3];  const void* bk = d_in[4];
    const void* Wv = d_in[5];  const void* bv = d_in[6];
    const void* Wo = d_in[7];  const void* bo = d_in[8];
    const void* rk = d_in[9];  const void* rv = d_in[10];

    int* flag = (int*)d_ws;
    const size_t HTD = (size_t)NH_ * T_ * D_;        // 4,194,304 elems
    unsigned short* qw = (unsigned short*)((char*)d_ws + 256);
    unsigned short* kw = qw + HTD;
    unsigned short* vw = kw + HTD;                   // V^T [N][D][T] bf16
    unsigned short* aw = vw + HTD;                   // [4096][1024] bf16 pre-Wo
    unsigned short* xw = aw + (size_t)M_ * E_;       // x as bf16 (8 MB)
    unsigned short* Ww = xw + (size_t)M_ * E_;       // Wq,Wk,Wv,Wo bf16 (8 MB)
    unsigned short* bw = Ww + (size_t)4 * E_ * E_;   // bq,bk,bv,bo bf16 (8 KB)
    // ws use: ~48 MB

    cvt_bf16<<<dim3((M_*E_/8 + 255)/256, 9), 256, 0, stream>>>(
        x, Wq, Wk, Wv, Wo, bq, bk, bv, bo, xw, Ww, bw, flag);
    qkv_gemm<<<dim3(768), 256, 0, stream>>>(xw, Ww, bw, qw, kw, vw);
    attn_mfma<<<dim3(NH_ * (T_/128)), 512, 0, stream>>>(qw, kw, vw, rk, rv, aw, flag);
    out_gemm<<<dim3(256), 256, 0, stream>>>(aw, Ww + (size_t)3*E_*E_, bw + 3*E_,
                                            d_out, flag);
}